// Round 6
// baseline (253.669 us; speedup 1.0000x reference)
//
#include <hip/hip_runtime.h>

typedef __attribute__((ext_vector_type(8))) short bf16x8;
typedef __attribute__((ext_vector_type(4))) float f32x4;
typedef unsigned short u16;
typedef unsigned int u32;
typedef __attribute__((address_space(1))) const u32 gu32;
typedef __attribute__((address_space(3))) u32 lu32;

__device__ __forceinline__ float bf2f(u16 u) {
  union { u32 i; float f; } c; c.i = ((u32)u) << 16; return c.f;
}
__device__ __forceinline__ u16 f2bf(float f) {
  union { float f; u32 i; } c; c.f = f;
  u32 u = c.i;
  u32 r = (u + 0x7FFFu + ((u >> 16) & 1u)) >> 16;  // RNE
  return (u16)r;
}

// async 16B global->LDS (linear dest: wave-uniform base + lane*16)
__device__ __forceinline__ void gld16(const void* g, void* l) {
  __builtin_amdgcn_global_load_lds((gu32*)g, (lu32*)l, 16, 0, 0);
}

// ---------------- CSR / normalization build ----------------

__global__ void k_count(const int* __restrict__ ei, int* deg, int E) {
  int e = blockIdx.x * 256 + threadIdx.x;
  if (e < E) atomicAdd(&deg[ei[E + e]], 1);  // dst = edge_index[1][e]
}

__global__ void k_blocksum(const int* __restrict__ deg, int* bsum, int n) {
  __shared__ int s[256];
  int t = threadIdx.x;
  int i = blockIdx.x * 256 + t;
  s[t] = (i < n) ? deg[i] : 0;  // deg = real-edge count (self-loop added later)
  __syncthreads();
  for (int o = 128; o > 0; o >>= 1) {
    if (t < o) s[t] += s[t + o];
    __syncthreads();
  }
  if (t == 0) bsum[blockIdx.x] = s[0];
}

__global__ void k_scanb(const int* __restrict__ bsum, int* bofs, int nb) {
  __shared__ int s[256];
  int t = threadIdx.x;
  int v = (t < nb) ? bsum[t] : 0;
  s[t] = v;
  __syncthreads();
  for (int o = 1; o < 256; o <<= 1) {
    int x = (t >= o) ? s[t - o] : 0;
    __syncthreads();
    s[t] += x;
    __syncthreads();
  }
  bofs[t] = s[t] - v;  // exclusive
}

__global__ void k_rowptr(const int* __restrict__ deg, const int* __restrict__ bofs,
                         int* rowptr, int* cursor, float* dinv, int n) {
  __shared__ int s[256];
  int t = threadIdx.x;
  int i = blockIdx.x * 256 + t;
  int v = (i < n) ? deg[i] : 0;
  s[t] = v;
  __syncthreads();
  for (int o = 1; o < 256; o <<= 1) {
    int x = (t >= o) ? s[t - o] : 0;
    __syncthreads();
    s[t] += x;
    __syncthreads();
  }
  int excl = s[t] - v + bofs[blockIdx.x];
  if (i < n) {
    rowptr[i] = excl;
    cursor[i] = excl;
    dinv[i] = rsqrtf((float)(v + 1));  // +1 self-loop
    if (i == n - 1) rowptr[n] = excl + v;
  }
}

// pack (src, dinv[src]) per edge
__global__ void k_fill(const int* __restrict__ ei, int* cursor,
                       const float* __restrict__ dinv, int2* colw, int E) {
  int e = blockIdx.x * 256 + threadIdx.x;
  if (e >= E) return;
  int s = ei[e];
  int d = ei[E + e];
  int pos = atomicAdd(&cursor[d], 1);
  colw[pos] = make_int2(s, __float_as_int(dinv[s]));
}

// transpose + bf16 both weights in one launch: W[K][N] f32 -> Wt[N][K] bf16
__global__ void k_twt2(const float* __restrict__ W1, u16* __restrict__ W1t,
                       const float* __restrict__ W2, u16* __restrict__ W2t) {
  int i = blockIdx.x * 256 + threadIdx.x;
  if (i < 512 * 256) {
    int k = i >> 8, n = i & 255;
    W1t[n * 512 + k] = f2bf(W1[i]);
  } else {
    int j = i - 512 * 256;
    if (j < 256 * 128) {
      int k = j >> 7, n = j & 127;
      W2t[n * 256 + k] = f2bf(W2[j]);
    }
  }
}

// ---------------- GEMM: C[M,ldc](bf16) = A[M,K] @ Bt[*,K]^T ----------------
// BM x 128 tile, BK=32, 4 waves (2x2 of (BM/2)x64). All staging via
// global_load_lds (pre-swizzled source, linear LDS dest, swizzled read).
// A stays fp32 in LDS when AF32 (cvt_pk on fragment read).
// K-loop: counted vmcnt + raw double barrier — tile t+1 loads stay in
// flight across the whole iteration (no vmcnt(0) drain).

template <bool AF32, int K, int BM, int MAXB>
__launch_bounds__(256, MAXB)
__global__ void gemm_kernel(const void* __restrict__ Ap, const u16* __restrict__ Bt,
                            u16* __restrict__ C, int M, int ldc) {
  constexpr int NT = K / 32;
  constexpr int ABYTES = BM * 32 * (AF32 ? 4 : 2);  // A bytes per buffer
  constexpr int AU16 = ABYTES / 2;
  constexpr int NJA = ABYTES / 4096;   // A gld16 per thread per stage
  constexpr int S = NJA + 2;           // per-thread vmem ops per stage
  constexpr int WROWS = BM / 2;
  constexpr int FI = WROWS / 16;
  __shared__ u16 As_[2][AU16];
  __shared__ u16 Bs_[2][4096];  // 128 x 32 bf16 per buffer

  const int tid = threadIdx.x;
  const int lane = tid & 63;
  const int wid = tid >> 6;
  const int wr = wid >> 1, wc = wid & 1;
  const long brow = (long)blockIdx.x * BM;
  const long bcol = (long)blockIdx.y * 128;

  // staging pointers: global pre-swizzled, LDS linear
  const char* agp[NJA];
  char* alp[NJA];
#pragma unroll
  for (int j = 0; j < NJA; ++j) {
    int idx = j * 256 + tid;  // 16B-unit index
    int row, u;
    if constexpr (AF32) { row = idx >> 3; u = (idx & 7) ^ (row & 7); }
    else                { row = idx >> 2; u = (idx & 3) ^ (row & 3); }
    long grow = brow + row; if (grow > (long)M - 1) grow = M - 1;
    agp[j] = (const char*)Ap + (grow * (long)K) * (AF32 ? 4 : 2) + u * 16;
    alp[j] = (char*)&As_[0][0] + idx * 16;
  }
  const u16* bgp[2];
  u16* blp[2];
#pragma unroll
  for (int j = 0; j < 2; ++j) {
    int idx = j * 256 + tid;
    int row = idx >> 2;
    int u = (idx & 3) ^ (row & 3);
    bgp[j] = Bt + (bcol + row) * (long)K + u * 8;
    blp[j] = &Bs_[0][idx * 8];
  }

  auto stage = [&](int kt, int buf) {
#pragma unroll
    for (int j = 0; j < NJA; ++j)
      gld16(agp[j] + kt * 32 * (AF32 ? 4 : 2), alp[j] + buf * ABYTES);
#pragma unroll
    for (int j = 0; j < 2; ++j) gld16(bgp[j] + kt * 32, blp[j] + buf * 4096);  // 4096 u16 = one buffer
  };

  f32x4 acc[FI][4];
#pragma unroll
  for (int i = 0; i < FI; i++)
#pragma unroll
    for (int j = 0; j < 4; j++) acc[i][j] = (f32x4){0.f, 0.f, 0.f, 0.f};

  stage(0, 0);
  int cur = 0;
  for (int kt = 0; kt < NT; ++kt) {
    if (kt + 1 < NT) {
      stage(kt + 1, cur ^ 1);
      asm volatile("s_waitcnt vmcnt(%0)" :: "n"(S) : "memory");  // my tile-kt loads done
    } else {
      asm volatile("s_waitcnt vmcnt(0)" ::: "memory");
    }
    __builtin_amdgcn_s_barrier();          // all waves' tile-kt loads visible
    __builtin_amdgcn_sched_barrier(0);

    bf16x8 af[FI], bfq[4];
#pragma unroll
    for (int i = 0; i < FI; i++) {
      const int row = wr * WROWS + i * 16 + (lane & 15);
      if constexpr (AF32) {
        const float* bp = (const float*)&As_[cur][0] + row * 32;
        const int s = row & 7;
        const int u0 = (lane >> 4) * 2;
        float4 x0 = *(const float4*)(bp + (u0 ^ s) * 4);
        float4 x1 = *(const float4*)(bp + ((u0 + 1) ^ s) * 4);
        union { u32 w[4]; bf16x8 v; } cv;
        asm("v_cvt_pk_bf16_f32 %0, %1, %2" : "=v"(cv.w[0]) : "v"(x0.x), "v"(x0.y));
        asm("v_cvt_pk_bf16_f32 %0, %1, %2" : "=v"(cv.w[1]) : "v"(x0.z), "v"(x0.w));
        asm("v_cvt_pk_bf16_f32 %0, %1, %2" : "=v"(cv.w[2]) : "v"(x1.x), "v"(x1.y));
        asm("v_cvt_pk_bf16_f32 %0, %1, %2" : "=v"(cv.w[3]) : "v"(x1.z), "v"(x1.w));
        af[i] = cv.v;
      } else {
        const int u = (lane >> 4) ^ (row & 3);
        af[i] = *(const bf16x8*)&As_[cur][row * 32 + u * 8];
      }
    }
#pragma unroll
    for (int j = 0; j < 4; j++) {
      const int row = wc * 64 + j * 16 + (lane & 15);
      const int u = (lane >> 4) ^ (row & 3);
      bfq[j] = *(const bf16x8*)&Bs_[cur][row * 32 + u * 8];
    }
#pragma unroll
    for (int i = 0; i < FI; i++)
#pragma unroll
      for (int j = 0; j < 4; j++)
        acc[i][j] = __builtin_amdgcn_mfma_f32_16x16x32_bf16(af[i], bfq[j], acc[i][j], 0, 0, 0);

    __builtin_amdgcn_sched_barrier(0);     // pin ds_reads above the barrier
    __builtin_amdgcn_s_barrier();          // all reads of buf cur done before restage
    cur ^= 1;
  }

#pragma unroll
  for (int i = 0; i < FI; i++) {
    const long r0 = brow + wr * WROWS + i * 16 + ((lane >> 4) * 4);
#pragma unroll
    for (int j = 0; j < 4; j++) {
      const long cc = bcol + wc * 64 + j * 16 + (lane & 15);
#pragma unroll
      for (int q = 0; q < 4; q++) {
        long r = r0 + q;
        if (r < M) C[r * (long)ldc + cc] = f2bf(acc[i][j][q]);
      }
    }
  }
}

// ---------------- Aggregation (one wave per node, full-row gather) ----------------

__device__ __forceinline__ float sigmoidf_(float x) { return 1.f / (1.f + __expf(-x)); }

__launch_bounds__(256)
__global__ void agg1(const u16* __restrict__ h0, const int* __restrict__ rowptr,
                     const int2* __restrict__ colw, const float* __restrict__ dinv,
                     const float* __restrict__ b1, u16* __restrict__ h, int n) {
  const int wid = threadIdx.x >> 6, lane = threadIdx.x & 63;
  const int node = blockIdx.x * 4 + wid;
  if (node >= n) return;
  const float di = dinv[node];
  ushort4 sv = ((const ushort4*)(h0 + (size_t)node * 256))[lane];
  float a0 = di * bf2f(sv.x), a1 = di * bf2f(sv.y), a2 = di * bf2f(sv.z), a3 = di * bf2f(sv.w);
  int e = rowptr[node];
  const int r1 = rowptr[node + 1];
  for (; e + 8 <= r1; e += 8) {
    int2 c[8];
#pragma unroll
    for (int q = 0; q < 8; ++q) c[q] = colw[e + q];
    ushort4 v[8];
#pragma unroll
    for (int q = 0; q < 8; ++q)
      v[q] = ((const ushort4*)(h0 + (size_t)c[q].x * 256))[lane];
#pragma unroll
    for (int q = 0; q < 8; ++q) {
      float wv = __int_as_float(c[q].y);
      a0 += wv * bf2f(v[q].x); a1 += wv * bf2f(v[q].y);
      a2 += wv * bf2f(v[q].z); a3 += wv * bf2f(v[q].w);
    }
  }
  for (; e < r1; ++e) {
    int2 c = colw[e];
    float wv = __int_as_float(c.y);
    ushort4 v = ((const ushort4*)(h0 + (size_t)c.x * 256))[lane];
    a0 += wv * bf2f(v.x); a1 += wv * bf2f(v.y); a2 += wv * bf2f(v.z); a3 += wv * bf2f(v.w);
  }
  float4 bb = ((const float4*)b1)[lane];
  a0 = a0 * di + bb.x; a1 = a1 * di + bb.y; a2 = a2 * di + bb.z; a3 = a3 * di + bb.w;
  a0 = fmaxf(a0, 0.f); a1 = fmaxf(a1, 0.f); a2 = fmaxf(a2, 0.f); a3 = fmaxf(a3, 0.f);
  ushort4 o; o.x = f2bf(a0); o.y = f2bf(a1); o.z = f2bf(a2); o.w = f2bf(a3);
  ((ushort4*)(h + (size_t)node * 256))[lane] = o;
}

__launch_bounds__(256)
__global__ void agg2(const u16* __restrict__ h2, const int* __restrict__ rowptr,
                     const int2* __restrict__ colw, const float* __restrict__ dinv,
                     const float* __restrict__ b2, float* __restrict__ out, int n) {
  const int wid = threadIdx.x >> 6, lane = threadIdx.x & 63;
  const int node = blockIdx.x * 4 + wid;
  if (node >= n) return;
  const float di = dinv[node];
  ushort2 sv = ((const ushort2*)(h2 + (size_t)node * 128))[lane];
  float a0 = di * bf2f(sv.x), a1 = di * bf2f(sv.y);
  int e = rowptr[node];
  const int r1 = rowptr[node + 1];
  for (; e + 8 <= r1; e += 8) {
    int2 c[8];
#pragma unroll
    for (int q = 0; q < 8; ++q) c[q] = colw[e + q];
    ushort2 v[8];
#pragma unroll
    for (int q = 0; q < 8; ++q)
      v[q] = ((const ushort2*)(h2 + (size_t)c[q].x * 128))[lane];
#pragma unroll
    for (int q = 0; q < 8; ++q) {
      float wv = __int_as_float(c[q].y);
      a0 += wv * bf2f(v[q].x); a1 += wv * bf2f(v[q].y);
    }
  }
  for (; e < r1; ++e) {
    int2 c = colw[e];
    float wv = __int_as_float(c.y);
    ushort2 v = ((const ushort2*)(h2 + (size_t)c.x * 128))[lane];
    a0 += wv * bf2f(v.x); a1 += wv * bf2f(v.y);
  }
  float2 bb = ((const float2*)b2)[lane];
  float2 o;
  o.x = sigmoidf_(a0 * di + bb.x);
  o.y = sigmoidf_(a1 * di + bb.y);
  ((float2*)(out + (size_t)node * 128))[lane] = o;
}

// ---------------- launch ----------------

extern "C" void kernel_launch(void* const* d_in, const int* in_sizes, int n_in,
                              void* d_out, int out_size, void* d_ws, size_t ws_size,
                              hipStream_t stream) {
  const float* x  = (const float*)d_in[0];
  const float* W1 = (const float*)d_in[1];
  const float* b1 = (const float*)d_in[2];
  const float* W2 = (const float*)d_in[3];
  const float* b2 = (const float*)d_in[4];
  const int*   ei = (const int*)d_in[5];

  const int N = in_sizes[0] / 512;
  const int E = in_sizes[5] / 2;
  const int Mpad = (N + 127) & ~127;
  float* outp = (float*)d_out;

  char* w = (char*)d_ws;
  size_t off = 0;
  auto take = [&](size_t bytes) -> void* {
    void* p = w + off;
    off = (off + bytes + 255) & ~(size_t)255;
    return p;
  };
  u16*   h0     = (u16*)take((size_t)Mpad * 256 * 2);
  u16*   hb     = (u16*)take((size_t)Mpad * 256 * 2);
  u16*   h2     = (u16*)take((size_t)Mpad * 128 * 2);
  u16*   W1t    = (u16*)take(256 * 512 * 2);
  u16*   W2t    = (u16*)take(128 * 256 * 2);
  int*   deg    = (int*)take((size_t)N * 4);
  float* dinv   = (float*)take((size_t)N * 4);
  int*   rowptr = (int*)take((size_t)(N + 1) * 4);
  int*   cursor = (int*)take((size_t)N * 4);
  int2*  colw   = (int2*)take((size_t)E * 8);
  int*   bsum   = (int*)take(256 * 4);
  int*   bofs   = (int*)take(256 * 4);
  (void)ws_size; (void)n_in; (void)out_size;

  const int nb = (N + 255) / 256;  // <=256 required by k_scanb
  const int eb = (E + 255) / 256;

  hipMemsetAsync(deg, 0, (size_t)N * 4, stream);
  k_count<<<eb, 256, 0, stream>>>(ei, deg, E);
  k_blocksum<<<nb, 256, 0, stream>>>(deg, bsum, N);
  k_scanb<<<1, 256, 0, stream>>>(bsum, bofs, nb);
  k_rowptr<<<nb, 256, 0, stream>>>(deg, bofs, rowptr, cursor, dinv, N);
  k_fill<<<eb, 256, 0, stream>>>(ei, cursor, dinv, colw, E);
  k_twt2<<<(512 * 256 + 256 * 128 + 255) / 256, 256, 0, stream>>>(W1, W1t, W2, W2t);

  dim3 g1(Mpad / 128, 2);
  gemm_kernel<true, 512, 128, 3><<<g1, 256, 0, stream>>>((const void*)x, W1t, h0, N, 256);
  agg1<<<(N + 3) / 4, 256, 0, stream>>>(h0, rowptr, colw, dinv, b1, hb, N);
  dim3 g2(Mpad / 64, 1);
  gemm_kernel<false, 256, 64, 4><<<g2, 256, 0, stream>>>((const void*)hb, W2t, h2, Mpad, 128);
  agg2<<<(N + 3) / 4, 256, 0, stream>>>(h2, rowptr, colw, dinv, b2, outp, N);
}